// Round 13
// baseline (1275.822 us; speedup 1.0000x reference)
//
#include <hip/hip_runtime.h>
#include <hip/hip_bf16.h>
#include <math.h>

// FactorizedVectorQuantizer MI355X (gfx950) — R13: R12 with three fixes:
// (1) prep bf16-split coverage bug (<<13 -> <<15; only 27% of whiG/wloG was
//     written, which also made replays read stale garbage from d_out scratch),
// (2) THR 1.2e-4 (2*Delta=6.8e-5 rigorous bound, 1.76x margin),
// (3) X LDS tiles in [khalf][row] layout -> conflict-free ds_write/A-reads.
//
// Soundness: exactD and approxD share Sp = (S + t); they differ only via the
// dot a. |a_mfma3 - a_serial| <= ~1.5e-6 (lo*lo + split residue + accum
// order) and each final fmaf rounds within ULP(D<256)/2 = 1.53e-5, so
// |approxD - exactD| <= Delta ~ 3.4e-5. Emit j if approxD_j <= blockMin + THR
// with THR = 1.2e-4 > 2*Delta: true min j* of block B has approxD_j* <=
// exactD_j* + Delta <= exactD_jB + Delta <= approxD_jB + 2*Delta < blockMin
// + THR. recheck_k re-evaluates candidates with the proven exact fp32 chain;
// packed-u64 min gives numpy's lowest-index tie-break.

#define NROWS   32768
#define NSHAPE  8192
#define NCOLOR  512
#define HALF    128
#define CAPS    208
#define THRF    1.2e-4f

// ws byte offsets (<= 856080, proven size)
#define OFF_TS    0u
#define OFF_TC    32768u
#define OFF_CNT_S 34816u
#define OFF_CNT_C 67584u
#define OFF_LOSS  69632u
#define OFF_SS    69648u
#define OFF_SC    200720u
#define OFF_BS    331792u           // u64[32768] (shape best, by recheck)
#define OFF_BC    593936u           // u64[32768] (color best, by color_exact)
#define OFF_WSEND 856080u

// d_out scratch byte offsets (every region read is fully rewritten each
// launch; finalize_k overwrites all of d_out afterwards)
#define OW_HI   0u                  // ushort[8192*128]
#define OW_LO   2097152u
#define OC_S    4194304u            // u32[32768*CAPS] = 27,262,976
#define OWCT    31457280u           // f32 Wct[128][512] color transpose
#define ORCS    31719424u           // u32[32768] shape cand counts
#define OEND    31850496u           // < 33,554,444

typedef __attribute__((address_space(3))) unsigned int  lds_u32;
typedef __attribute__((address_space(1))) const unsigned int gbl_u32;
typedef __attribute__((ext_vector_type(8)))  short short8v;
typedef __attribute__((ext_vector_type(16))) float f32x16;

__device__ __forceinline__ unsigned mono_f32(float d) {
    unsigned u = __float_as_uint(d);
    return (u & 0x80000000u) ? ~u : (u | 0x80000000u);
}
__device__ __forceinline__ unsigned short rne_bf16(float v) {
    unsigned u = __float_as_uint(v);
    unsigned r = u + 0x7FFFu + ((u >> 16) & 1u);
    return (unsigned short)(r >> 16);
}
__device__ __forceinline__ float bf16_f(unsigned short h) {
    return __uint_as_float(((unsigned)h) << 16);
}

// ---- prep: codes_sq(34) | rows_sq(128) | W bf16 split(32) | Wct color T(32)
__global__ __launch_bounds__(256) void prep_k(
    const float* __restrict__ Ws, const float* __restrict__ Wc,
    const float* __restrict__ input,
    float* __restrict__ ts, float* __restrict__ tc,
    float* __restrict__ Ss, float* __restrict__ Sc,
    unsigned short* __restrict__ whiG, unsigned short* __restrict__ wloG,
    float* __restrict__ Wct)
{
    __shared__ float tile[32][65];
    int blk = blockIdx.x, tid = threadIdx.x;
    if (blk < 34) {
        int j = blk * 256 + tid;
        const float* w; int jl;
        if (j < NSHAPE) { w = Ws + (size_t)j * HALF; jl = j; }
        else            { w = Wc + (size_t)(j - NSHAPE) * HALF; jl = j - NSHAPE; }
        float s = 0.f;
        #pragma unroll
        for (int k = 0; k < HALF; ++k) s = fmaf(w[k], w[k], s);
        if (j < NSHAPE) ts[jl] = s; else tc[jl] = s;
    } else if (blk < 162) {
        int r = (blk - 34) * 256 + tid;
        int b = r >> 10, hw = r & 1023;
        const float* __restrict__ xin = input + ((size_t)b << 18) + hw;
        float s = 0.f;
        #pragma unroll
        for (int k = 0; k < HALF; ++k) { float v = xin[(size_t)k << 10]; s = fmaf(v, v, s); }
        Ss[r] = s;
        float s2 = 0.f;
        #pragma unroll
        for (int k = 0; k < HALF; ++k) { float v = xin[(size_t)(k + HALF) << 10]; s2 = fmaf(v, v, s2); }
        Sc[r] = s2;
    } else if (blk < 194) {
        // shape codebook bf16 hi/lo split: block = 256 codes = 32768 floats
        size_t f0 = ((size_t)(blk - 162)) << 15;   // FIXED: was <<13 (overlap!)
        for (int it = 0; it < 32; ++it) {
            size_t fi = f0 + ((size_t)(it * 256 + tid) << 2);
            float4 v = *(const float4*)(Ws + fi);
            unsigned short h0 = rne_bf16(v.x), h1 = rne_bf16(v.y);
            unsigned short h2 = rne_bf16(v.z), h3 = rne_bf16(v.w);
            ushort4 hv = make_ushort4(h0, h1, h2, h3);
            ushort4 lv = make_ushort4(rne_bf16(v.x - bf16_f(h0)),
                                      rne_bf16(v.y - bf16_f(h1)),
                                      rne_bf16(v.z - bf16_f(h2)),
                                      rne_bf16(v.w - bf16_f(h3)));
            *(ushort4*)(whiG + fi) = hv;
            *(ushort4*)(wloG + fi) = lv;
        }
    } else {
        // color codebook fp32 transpose: Wct[k][512]
        int b2 = blk - 194;
        int c0 = (b2 & 7) << 6, k0 = (b2 >> 3) << 5;
        int kk = tid & 31, cc = tid >> 5;
        #pragma unroll
        for (int p = 0; p < 8; ++p) {
            int c = cc + (p << 3);
            tile[kk][c] = Wc[(size_t)(c0 + c) * HALF + k0 + kk];
        }
        __syncthreads();
        int c2 = tid & 63, kr0 = (tid >> 6) << 3;
        #pragma unroll
        for (int p = 0; p < 8; ++p) {
            int kr = kr0 + p;
            Wct[(size_t)(k0 + kr) * 512 + c0 + c2] = tile[kr][c2];
        }
    }
}

// ---- approx MFMA filter: block = 128 rows x 256 shape codes ----
__global__ __launch_bounds__(256, 2) void approx_k(
    const float* __restrict__ input,
    const unsigned short* __restrict__ whiG, const unsigned short* __restrict__ wloG,
    const float* __restrict__ ts, const float* __restrict__ Ss,
    unsigned* __restrict__ rcS, unsigned* __restrict__ candS)
{
    __shared__ __align__(16) char smem[28672];
    // XH/XL: [kh][row] chunks (chunk = kh*128+row) -> conflict-free writes/reads
    // WH/WL: DMA-linear (chunk = code*2+kh)
    short8v* XH = (short8v*)(smem);
    short8v* XL = (short8v*)(smem + 4096);
    short8v* WH = (short8v*)(smem + 8192);
    short8v* WL = (short8v*)(smem + 16384);
    float* red    = (float*)(smem + 24576);   // [128][5]
    float* rowthr = (float*)(smem + 27136);
    float* sld    = (float*)(smem + 27648);

    int d = blockIdx.x;
    int o = (d & 7) * 1024 + (d >> 3);          // XCD swizzle, 8192 blocks
    int rowblk = o >> 5, colblk = o & 31;
    int cg0 = colblk << 8;                      // 256 codes
    int r0 = rowblk << 7;
    int b = r0 >> 10, hw0 = r0 & 1023;

    int tid = threadIdx.x;
    int lane = tid & 63;
    int wv = __builtin_amdgcn_readfirstlane(tid >> 6);
    int l31 = lane & 31, lh = lane >> 5;

    if (tid < 128) sld[tid] = Ss[r0 + tid];

    const float* __restrict__ xg = input + ((size_t)b << 18) + hw0;
    int row = tid & 127, kh8 = (tid >> 7) << 3;

    f32x16 acc[4][2];
    #pragma unroll
    for (int rt = 0; rt < 4; ++rt)
        #pragma unroll
        for (int ct = 0; ct < 2; ++ct)
            #pragma unroll
            for (int e = 0; e < 16; ++e) acc[rt][ct][e] = 0.f;

    for (int ks = 0; ks < 8; ++ks) {
        int k0 = ks << 4;
        if (ks) __syncthreads();   // all waves done reading previous slab
        // DMA W hi/lo slabs (latency hides under X load+convert below)
        #pragma unroll
        for (int i = 0; i < 2; ++i) {
            int C = wv * 128 + i * 64 + lane;   // dest chunk, affine in lane
            int code = C >> 1, kh = C & 1;
            size_t so = ((size_t)(cg0 + code) << 7) + k0 + (kh << 3);
            __builtin_amdgcn_global_load_lds(
                (gbl_u32*)(whiG + so), (lds_u32*)((char*)WH + (size_t)C * 16), 16, 0, 0);
            __builtin_amdgcn_global_load_lds(
                (gbl_u32*)(wloG + so), (lds_u32*)((char*)WL + (size_t)C * 16), 16, 0, 0);
        }
        // X load (coalesced) + bf16 hi/lo split; chunk = tid = kh*128+row
        float xv[8];
        #pragma unroll
        for (int p = 0; p < 8; ++p)
            xv[p] = xg[((size_t)(k0 + kh8 + p) << 10) + row];
        short8v hv, lv;
        #pragma unroll
        for (int p = 0; p < 8; ++p) {
            unsigned short h = rne_bf16(xv[p]);
            hv[p] = (short)h;
            lv[p] = (short)rne_bf16(xv[p] - bf16_f(h));
        }
        XH[tid] = hv;
        XL[tid] = lv;
        __syncthreads();           // drains DMA (vmcnt0) + LDS writes

        // fragments (32x32x16): A row = lane&31, k = (lane>>5)*8+j;
        // B col = lane&31, same k rule -> any in-slab k permutation cancels.
        short8v Ah[4], Al[4], Bh[2], Bl[2];
        #pragma unroll
        for (int rt = 0; rt < 4; ++rt) {
            int ch = lh * 128 + rt * 32 + l31;
            Ah[rt] = XH[ch]; Al[rt] = XL[ch];
        }
        #pragma unroll
        for (int ct = 0; ct < 2; ++ct) {
            int cc = (wv * 64 + ct * 32 + l31) * 2 + lh;
            Bh[ct] = WH[cc]; Bl[ct] = WL[cc];
        }
        #pragma unroll
        for (int rt = 0; rt < 4; ++rt)
            #pragma unroll
            for (int ct = 0; ct < 2; ++ct) {
                acc[rt][ct] = __builtin_amdgcn_mfma_f32_32x32x16_bf16(
                    Ah[rt], Bh[ct], acc[rt][ct], 0, 0, 0);
                acc[rt][ct] = __builtin_amdgcn_mfma_f32_32x32x16_bf16(
                    Ah[rt], Bl[ct], acc[rt][ct], 0, 0, 0);
                acc[rt][ct] = __builtin_amdgcn_mfma_f32_32x32x16_bf16(
                    Al[rt], Bh[ct], acc[rt][ct], 0, 0, 0);
            }
    }
    __syncthreads();

    float tld[2];
    #pragma unroll
    for (int ct = 0; ct < 2; ++ct)
        tld[ct] = ts[cg0 + wv * 64 + ct * 32 + l31];

    // per-(rt,reg) min over ct, then butterfly min across the 32-lane half
    float vmin[4][16];
    #pragma unroll
    for (int rt = 0; rt < 4; ++rt)
        #pragma unroll
        for (int q = 0; q < 16; ++q) {
            int rr = (q & 3) + 8 * (q >> 2) + 4 * lh;
            float Sv = sld[rt * 32 + rr];
            float d0 = fmaf(-2.0f, acc[rt][0][q], Sv + tld[0]);
            float d1 = fmaf(-2.0f, acc[rt][1][q], Sv + tld[1]);
            vmin[rt][q] = fminf(d0, d1);
        }
    #pragma unroll
    for (int m = 1; m < 32; m <<= 1)
        #pragma unroll
        for (int rt = 0; rt < 4; ++rt)
            #pragma unroll
            for (int q = 0; q < 16; ++q)
                vmin[rt][q] = fminf(vmin[rt][q], __shfl_xor(vmin[rt][q], m, 64));
    if (l31 == 0) {
        #pragma unroll
        for (int rt = 0; rt < 4; ++rt)
            #pragma unroll
            for (int q = 0; q < 16; ++q) {
                int rr = (q & 3) + 8 * (q >> 2) + 4 * lh;
                red[(rt * 32 + rr) * 5 + wv] = vmin[rt][q];
            }
    }
    __syncthreads();
    if (tid < 128) {
        float m0 = fminf(fminf(red[tid * 5 + 0], red[tid * 5 + 1]),
                         fminf(red[tid * 5 + 2], red[tid * 5 + 3]));
        rowthr[tid] = m0 + THRF;
    }
    __syncthreads();

    // candidate emission (block-local min always within threshold of itself)
    #pragma unroll
    for (int rt = 0; rt < 4; ++rt)
        #pragma unroll
        for (int ct = 0; ct < 2; ++ct)
            #pragma unroll
            for (int q = 0; q < 16; ++q) {
                int rr = rt * 32 + (q & 3) + 8 * (q >> 2) + 4 * lh;
                float D = fmaf(-2.0f, acc[rt][ct][q], sld[rr] + tld[ct]);
                if (D <= rowthr[rr]) {
                    int cg = cg0 + wv * 64 + ct * 32 + l31;
                    unsigned idx = atomicAdd(&rcS[r0 + rr], 1u);
                    if (idx < CAPS) candS[(size_t)(r0 + rr) * CAPS + idx] = (unsigned)cg;
                }
            }
}

// ---- color: exact fp32 GEMM argmin (R8-proven structure, color book only) --
#define FMA_ROW(i, xv) \
    acc[i][0] = fmaf(xv, w0.x, acc[i][0]); acc[i][1] = fmaf(xv, w0.y, acc[i][1]); \
    acc[i][2] = fmaf(xv, w0.z, acc[i][2]); acc[i][3] = fmaf(xv, w0.w, acc[i][3]); \
    acc[i][4] = fmaf(xv, w1.x, acc[i][4]); acc[i][5] = fmaf(xv, w1.y, acc[i][5]); \
    acc[i][6] = fmaf(xv, w1.z, acc[i][6]); acc[i][7] = fmaf(xv, w1.w, acc[i][7]);

__global__ __launch_bounds__(256, 4) void color_exact_k(
    const float* __restrict__ input, const float* __restrict__ wct,
    const float* __restrict__ tc, const float* __restrict__ Sc,
    unsigned long long* __restrict__ bc)
{
    __shared__ __align__(16) char smem[32768];
    float (*xs2)[16][128] = reinterpret_cast<float(*)[16][128]>(smem);
    float (*ws2)[16][128] = reinterpret_cast<float(*)[16][128]>(smem + 16384);

    int d = blockIdx.x;
    int o = (d & 7) * 128 + (d >> 3);           // 1024 blocks
    int rowblk = o >> 2, cb = o & 3;
    int c0 = cb << 7;
    int tid = threadIdx.x;
    int lane = tid & 63;
    int wv = __builtin_amdgcn_readfirstlane(tid >> 6);
    int r0 = rowblk << 7;
    int b = r0 >> 10, hw0 = r0 & 1023;

    const float* __restrict__ xg =
        input + ((size_t)b << 18) + ((size_t)HALF << 10) + hw0
              + ((size_t)(lane >> 5) << 10) + ((lane & 31) << 2);
    const float* __restrict__ wg =
        wct + (size_t)(lane >> 5) * 512 + c0 + ((lane & 31) << 2);

    int tr = tid & 15, tcg = tid >> 4;
    int tr4 = tr << 2, tc4 = tcg << 2;
    int kw = wv << 2;

    float acc[8][8] = {{0.f}};

    #pragma unroll
    for (int i = 0; i < 2; ++i) {
        int kx = kw + (i << 1);
        __builtin_amdgcn_global_load_lds(
            (gbl_u32*)(xg + ((size_t)kx << 10)), (lds_u32*)&xs2[0][kx][0], 16, 0, 0);
        __builtin_amdgcn_global_load_lds(
            (gbl_u32*)(wg + (size_t)kx * 512), (lds_u32*)&ws2[0][kx][0], 16, 0, 0);
    }
    __syncthreads();

    for (int s = 0; s < 8; ++s) {
        if (s < 7) {
            int k0 = (s + 1) << 4;
            #pragma unroll
            for (int i = 0; i < 2; ++i) {
                int kx = kw + (i << 1);
                __builtin_amdgcn_global_load_lds(
                    (gbl_u32*)(xg + ((size_t)(k0 + kx) << 10)),
                    (lds_u32*)&xs2[(s + 1) & 1][kx][0], 16, 0, 0);
                __builtin_amdgcn_global_load_lds(
                    (gbl_u32*)(wg + (size_t)(k0 + kx) * 512),
                    (lds_u32*)&ws2[(s + 1) & 1][kx][0], 16, 0, 0);
            }
        }
        const float (*xsb)[128] = xs2[s & 1];
        const float (*wtb)[128] = ws2[s & 1];
        #pragma unroll 8
        for (int k = 0; k < 16; ++k) {
            const float4 x0 = *(const float4*)&xsb[k][tr4];
            const float4 x1 = *(const float4*)&xsb[k][64 + tr4];
            const float4 w0 = *(const float4*)&wtb[k][tc4];
            const float4 w1 = *(const float4*)&wtb[k][64 + tc4];
            FMA_ROW(0, x0.x) FMA_ROW(1, x0.y) FMA_ROW(2, x0.z) FMA_ROW(3, x0.w)
            FMA_ROW(4, x1.x) FMA_ROW(5, x1.y) FMA_ROW(6, x1.z) FMA_ROW(7, x1.w)
        }
        __syncthreads();
    }

    float Sr[8];
    #pragma unroll
    for (int i = 0; i < 8; ++i) {
        int rl = ((i & 4) << 4) + tr4 + (i & 3);
        Sr[i] = Sc[r0 + rl];
    }
    float bestD[8]; int bestC[8];
    #pragma unroll
    for (int i = 0; i < 8; ++i) { bestD[i] = INFINITY; bestC[i] = 0; }
    #pragma unroll
    for (int j = 0; j < 8; ++j) {
        int cl = ((j & 4) << 4) + tc4 + (j & 3);
        int cgj = c0 + cl;
        float tj = tc[cgj];
        #pragma unroll
        for (int i = 0; i < 8; ++i) {
            float Sp = Sr[i] + tj;
            float D = fmaf(-2.0f, acc[i][j], Sp);
            if (D < bestD[i]) { bestD[i] = D; bestC[i] = cgj; }
        }
    }
    __syncthreads();
    unsigned long long* red = reinterpret_cast<unsigned long long*>(smem);
    #pragma unroll
    for (int i = 0; i < 8; ++i) {
        int rl = ((i & 4) << 4) + tr4 + (i & 3);
        red[rl * 17 + tcg] =
            ((unsigned long long)mono_f32(bestD[i]) << 32) | (unsigned)bestC[i];
    }
    __syncthreads();
    if (tid < 128) {
        unsigned long long m = red[tid * 17];
        #pragma unroll
        for (int q = 1; q < 16; ++q) {
            unsigned long long v = red[tid * 17 + q];
            if (v < m) m = v;
        }
        atomicMin(&bc[r0 + tid], m);
    }
}

// ---- exact recheck of shape candidates (proven fp32 pipeline) ----
__global__ __launch_bounds__(256) void recheck_k(
    const float* __restrict__ input, const float* __restrict__ Ws,
    const float* __restrict__ ts, const float* __restrict__ Ss,
    const unsigned* __restrict__ rcS, const unsigned* __restrict__ candS,
    unsigned long long* __restrict__ bs)
{
    __shared__ float xsh[32][132];
    int r0b = blockIdx.x << 5;
    int tid = threadIdx.x;
    int b = r0b >> 10, hw0 = r0b & 1023;
    for (int pass = 0; pass < 16; ++pass) {
        int k = pass * 8 + (tid >> 5), rl = tid & 31;
        xsh[rl][k] = input[((size_t)b << 18) + ((size_t)k << 10) + hw0 + rl];
    }
    __syncthreads();
    int g = tid >> 3, j8 = tid & 7;
    int r = r0b + g;
    unsigned n = rcS[r];
    bool full = (n == 0u) || (n > CAPS);
    int ne = full ? NSHAPE : (int)n;
    float Sv = Ss[r];
    const float4* x4 = (const float4*)&xsh[g][0];
    unsigned long long best = ~0ull;
    for (int c = j8; c < ne; c += 8) {
        int code = full ? c : (int)candS[(size_t)r * CAPS + c];
        const float4* w4 = (const float4*)(Ws + ((size_t)code << 7));
        float a = 0.f;
        #pragma unroll
        for (int q = 0; q < 32; ++q) {      // serial ascending-k fp32 chain
            float4 xq = x4[q];
            float4 wq = w4[q];
            a = fmaf(xq.x, wq.x, a); a = fmaf(xq.y, wq.y, a);
            a = fmaf(xq.z, wq.z, a); a = fmaf(xq.w, wq.w, a);
        }
        float D = fmaf(-2.0f, a, Sv + ts[code]);
        unsigned long long p = ((unsigned long long)mono_f32(D) << 32) | (unsigned)code;
        if (p < best) best = p;
    }
    #pragma unroll
    for (int m = 1; m < 8; m <<= 1) {
        unsigned long long v = __shfl_xor(best, m, 64);
        if (v < best) best = v;
    }
    if (j8 == 0) bs[r] = best;
}

__global__ __launch_bounds__(256) void finalize_k(
    const float* __restrict__ input,
    const float* __restrict__ Ws, const float* __restrict__ Wc,
    const unsigned long long* __restrict__ bs,
    const unsigned long long* __restrict__ bc,
    unsigned* __restrict__ cnt_s, unsigned* __restrict__ cnt_c,
    double* __restrict__ loss_sum, float* __restrict__ out)
{
    int tid = threadIdx.x;
    int r = blockIdx.x * 256 + tid;
    int bi = (int)(bs[r] & 0xFFFFFFFFu);
    int ci = (int)(bc[r] & 0xFFFFFFFFu);
    atomicAdd(&cnt_s[bi], 1u);
    atomicAdd(&cnt_c[ci], 1u);

    int b = r >> 10; int hw = r & 1023;
    const float* __restrict__ xin = input + ((size_t)b << 18) + hw;
    float* __restrict__ op = out + ((size_t)b << 18) + hw;
    const float* __restrict__ qs = Ws + ((size_t)bi << 7);
    const float* __restrict__ qc = Wc + ((size_t)ci << 7);

    double ls = 0.0;
    #pragma unroll 8
    for (int c = 0; c < HALF; ++c) {
        float f = xin[(size_t)c << 10];
        float dd = qs[c] - f;                  // fp32(q - f)
        op[(size_t)c << 10] = f + dd;          // fp32(f + fp32(q - f))
        ls += (double)dd * (double)dd;
    }
    #pragma unroll 8
    for (int c = 0; c < HALF; ++c) {
        float f = xin[(size_t)(c + HALF) << 10];
        float dd = qc[c] - f;
        op[(size_t)(c + HALF) << 10] = f + dd;
        ls += (double)dd * (double)dd;
    }
    __shared__ double red[256];
    red[tid] = ls;
    __syncthreads();
    for (int s = 128; s > 0; s >>= 1) {
        if (tid < s) red[tid] += red[tid + s];
        __syncthreads();
    }
    if (tid == 0) atomicAdd(loss_sum, red[0]);
}

__global__ __launch_bounds__(256) void scalars_k(
    const unsigned* __restrict__ cnt_s, const unsigned* __restrict__ cnt_c,
    const double* __restrict__ loss_sum, float* __restrict__ out3)
{
    int tid = threadIdx.x;
    double es = 0.0, ec = 0.0;
    for (int j = tid; j < NSHAPE; j += 256) {
        float p = (float)cnt_s[j] / 32768.0f;
        es += (double)(p * logf(p + 1e-10f));
    }
    for (int j = tid; j < NCOLOR; j += 256) {
        float p = (float)cnt_c[j] / 32768.0f;
        ec += (double)(p * logf(p + 1e-10f));
    }
    __shared__ double r1[256], r2[256];
    r1[tid] = es; r2[tid] = ec;
    __syncthreads();
    for (int s = 128; s > 0; s >>= 1) {
        if (tid < s) { r1[tid] += r1[tid + s]; r2[tid] += r2[tid + s]; }
        __syncthreads();
    }
    if (tid == 0) {
        out3[0] = (float)(1.25 * loss_sum[0] / 8388608.0);
        out3[1] = expf(-(float)r1[0]);
        out3[2] = expf(-(float)r2[0]);
    }
}

extern "C" void kernel_launch(void* const* d_in, const int* in_sizes, int n_in,
                              void* d_out, int out_size, void* d_ws, size_t ws_size,
                              hipStream_t stream)
{
    const float* input = (const float*)d_in[0];
    const float* Ws    = (const float*)d_in[1];
    const float* Wc    = (const float*)d_in[2];
    float* out = (float*)d_out;
    char* ws = (char*)d_ws;
    char* ob = (char*)d_out;

    float*    ts       = (float*)(ws + OFF_TS);
    float*    tcx      = (float*)(ws + OFF_TC);
    unsigned* cnt_s    = (unsigned*)(ws + OFF_CNT_S);
    unsigned* cnt_c    = (unsigned*)(ws + OFF_CNT_C);
    double*   loss_sum = (double*)(ws + OFF_LOSS);
    float*    Ss       = (float*)(ws + OFF_SS);
    float*    Sc       = (float*)(ws + OFF_SC);
    unsigned long long* bs = (unsigned long long*)(ws + OFF_BS);
    unsigned long long* bc = (unsigned long long*)(ws + OFF_BC);

    unsigned short* whiG = (unsigned short*)(ob + OW_HI);
    unsigned short* wloG = (unsigned short*)(ob + OW_LO);
    unsigned*       candS = (unsigned*)(ob + OC_S);
    float*          Wct   = (float*)(ob + OWCT);
    unsigned*       rcS   = (unsigned*)(ob + ORCS);

    // zero hist counts + loss; sentinel bs/bc; zero shape cand counts
    hipMemsetAsync(ws + OFF_CNT_S, 0, (OFF_LOSS + 8u) - OFF_CNT_S, stream);
    hipMemsetAsync(ws + OFF_BS, 0xFF, OFF_WSEND - OFF_BS, stream);
    hipMemsetAsync(ob + ORCS, 0, 131072u, stream);

    prep_k<<<226, 256, 0, stream>>>(Ws, Wc, input, ts, tcx, Ss, Sc,
                                    whiG, wloG, Wct);

    approx_k<<<8192, 256, 0, stream>>>(input, whiG, wloG, ts, Ss, rcS, candS);

    color_exact_k<<<1024, 256, 0, stream>>>(input, Wct, tcx, Sc, bc);

    recheck_k<<<1024, 256, 0, stream>>>(input, Ws, ts, Ss, rcS, candS, bs);

    finalize_k<<<NROWS / 256, 256, 0, stream>>>(
        input, Ws, Wc, bs, bc, cnt_s, cnt_c, loss_sum, out);

    scalars_k<<<1, 256, 0, stream>>>(cnt_s, cnt_c, loss_sum, out + 8388608);
}